// Round 2
// baseline (1129.933 us; speedup 1.0000x reference)
//
#include <hip/hip_runtime.h>
#include <stdint.h>

#define N 8192
#define D 256
#define L 4
#define K 1024
#define E 8

// distance-kernel tiling
#define TM 128            // samples per tile
#define TK 128            // codes per block (K split across blocks)
#define BD 64             // d-chunk staged in LDS
#define KSPLIT (K / TK)   // 8
#define MAXTILES (N / TM + E)   // 72 (ragged per-expert tiles)
#define PADF 68           // LDS row stride in floats (64 + 4 pad)

typedef unsigned long long u64;

__device__ __forceinline__ unsigned f2sort(float f) {
    unsigned u = __float_as_uint(f);
    return (u & 0x80000000u) ? ~u : (u | 0x80000000u);
}

// ---------------------------------------------------------------- gate ------
// one wave per sample: logits = x@W + b, expert = argmax (first max wins)
__global__ void gate_kernel(const float* __restrict__ x,
                            const float* __restrict__ gW,
                            const float* __restrict__ gb,
                            int* __restrict__ eid, int* __restrict__ counts,
                            float* __restrict__ out_idx /* -> indices[n][4] */) {
    int wid = threadIdx.x >> 6, lane = threadIdx.x & 63;
    int n = blockIdx.x * 4 + wid;
    float4 xv = *reinterpret_cast<const float4*>(x + (size_t)n * D + lane * 4);
    float xa[4] = {xv.x, xv.y, xv.z, xv.w};
    float a[8];
#pragma unroll
    for (int e = 0; e < 8; e++) a[e] = 0.f;
    const float* wr = gW + (size_t)(lane * 4) * E;
#pragma unroll
    for (int i = 0; i < 4; i++) {
        float xs = xa[i];
        float4 w0 = *reinterpret_cast<const float4*>(wr + i * E);
        float4 w1 = *reinterpret_cast<const float4*>(wr + i * E + 4);
        a[0] = fmaf(xs, w0.x, a[0]); a[1] = fmaf(xs, w0.y, a[1]);
        a[2] = fmaf(xs, w0.z, a[2]); a[3] = fmaf(xs, w0.w, a[3]);
        a[4] = fmaf(xs, w1.x, a[4]); a[5] = fmaf(xs, w1.y, a[5]);
        a[6] = fmaf(xs, w1.z, a[6]); a[7] = fmaf(xs, w1.w, a[7]);
    }
#pragma unroll
    for (int off = 32; off > 0; off >>= 1) {
#pragma unroll
        for (int e = 0; e < 8; e++) a[e] += __shfl_xor(a[e], off);
    }
    if (lane == 0) {
        int be = 0;
        float bv = a[0] + gb[0];
        for (int e = 1; e < 8; e++) {
            float v = a[e] + gb[e];
            if (v > bv) { bv = v; be = e; }   // strict >: first max wins, matches argmax
        }
        eid[n] = be;
        out_idx[(size_t)n * (L + 1) + L] = (float)be;
        atomicAdd(&counts[be], 1);
    }
}

// ----------------------------------------------------------- c2 = ||c||^2 ---
__global__ void c2_kernel(const float* __restrict__ cbs, float* __restrict__ c2) {
    int wid = threadIdx.x >> 6, lane = threadIdx.x & 63;
    int row = blockIdx.x * 4 + wid;   // row in [0, L*E*K)
    float4 v = *reinterpret_cast<const float4*>(cbs + (size_t)row * D + lane * 4);
    float s = v.x * v.x + v.y * v.y + v.z * v.z + v.w * v.w;
#pragma unroll
    for (int off = 32; off > 0; off >>= 1) s += __shfl_xor(s, off);
    if (lane == 0) c2[row] = s;
}

// --------------------------------------------------------- bucket by expert -
__global__ void offsets_kernel(const int* __restrict__ counts, int* __restrict__ eoff) {
    if (threadIdx.x == 0) {
        int a = 0;
        for (int e = 0; e < E; e++) { eoff[e] = a; a += counts[e]; }
        eoff[E] = a;
    }
}

__global__ void scatter_kernel(const int* __restrict__ eid, const int* __restrict__ eoff,
                               int* __restrict__ cursors, int* __restrict__ order) {
    int n = blockIdx.x * 256 + threadIdx.x;
    int e = eid[n];
    int pos = atomicAdd(&cursors[e], 1);
    order[eoff[e] + pos] = n;
}

// ------------------------------------------------------------- distances ----
// block = (sample tile of 128 within one expert) x (128 codes).
// 256 threads, 8x8 micro-tile each. fp32 accumulate; dist = c2 - 2*dot.
// per-sample winner combined across KSPLIT blocks via atomicMin on packed key.
__global__ __launch_bounds__(256, 2)
void dist_kernel(const float* __restrict__ rin, const float* __restrict__ cbl,
                 const float* __restrict__ c2l, const int* __restrict__ order,
                 const int* __restrict__ eoff, u64* __restrict__ keys) {
    __shared__ float lr[TM * PADF];
    __shared__ float lc[TK * PADF];

    int bx = blockIdx.x;
    int tile = bx / KSPLIT, kc = bx % KSPLIT;

    // locate (expert, local tile) — ragged tile table scanned on the fly
    int e = -1, lt = 0, cnt = 0, cum = 0;
    for (int i = 0; i < E; i++) {
        int c0 = eoff[i], c1 = eoff[i + 1];
        int t = (c1 - c0 + TM - 1) / TM;
        if (tile < cum + t) { e = i; lt = tile - cum; cnt = c1 - c0; break; }
        cum += t;
    }
    if (e < 0) return;
    int base = eoff[e] + lt * TM;
    int mcnt = min(TM, cnt - lt * TM);
    int k0 = kc * TK;
    const float* cb = cbl + ((size_t)e * K + k0) * D;

    int tid = threadIdx.x;
    int tk = tid & 15, ts = tid >> 4;

    float facc[8][8];
#pragma unroll
    for (int i = 0; i < 8; i++)
#pragma unroll
        for (int j = 0; j < 8; j++) facc[i][j] = 0.f;

    for (int dc = 0; dc < D; dc += BD) {
        __syncthreads();
        // stage residual tile (zeros for ragged rows); XOR-swizzle f4 index
#pragma unroll
        for (int it = 0; it < (TM * BD / 4) / 256; it++) {
            int g = tid + it * 256;
            int row = g >> 4, q = g & 15;
            int qs = q ^ ((row >> 3) & 7);
            float4 v = make_float4(0.f, 0.f, 0.f, 0.f);
            if (row < mcnt) {
                int n = order[base + row];
                v = *reinterpret_cast<const float4*>(rin + (size_t)n * D + dc + q * 4);
            }
            *reinterpret_cast<float4*>(&lr[row * PADF + qs * 4]) = v;
        }
        // stage code tile
#pragma unroll
        for (int it = 0; it < (TK * BD / 4) / 256; it++) {
            int g = tid + it * 256;
            int row = g >> 4, q = g & 15;
            int qs = q ^ ((row >> 3) & 7);
            float4 v = *reinterpret_cast<const float4*>(cb + (size_t)row * D + dc + q * 4);
            *reinterpret_cast<float4*>(&lc[row * PADF + qs * 4]) = v;
        }
        __syncthreads();
#pragma unroll 2
        for (int q = 0; q < 16; q++) {
            float4 r4[8], c4[8];
#pragma unroll
            for (int i = 0; i < 8; i++) {
                int row = ts * 8 + i;
                r4[i] = *reinterpret_cast<const float4*>(
                    &lr[row * PADF + (q ^ ((row >> 3) & 7)) * 4]);
            }
#pragma unroll
            for (int j = 0; j < 8; j++) {
                int row = tk * 8 + j;
                c4[j] = *reinterpret_cast<const float4*>(
                    &lc[row * PADF + (q ^ ((row >> 3) & 7)) * 4]);
            }
#pragma unroll
            for (int i = 0; i < 8; i++)
#pragma unroll
                for (int j = 0; j < 8; j++) {
                    facc[i][j] = fmaf(r4[i].x, c4[j].x, facc[i][j]);
                    facc[i][j] = fmaf(r4[i].y, c4[j].y, facc[i][j]);
                    facc[i][j] = fmaf(r4[i].z, c4[j].z, facc[i][j]);
                    facc[i][j] = fmaf(r4[i].w, c4[j].w, facc[i][j]);
                }
        }
    }

    // epilogue: dist = c2 - 2*dot, local min, 16-lane reduce, one atomic/sample
    const float* c2p = c2l + (size_t)e * K + k0;
#pragma unroll
    for (int i = 0; i < 8; i++) {
        int row = ts * 8 + i;
        u64 best = ~0ull;
#pragma unroll
        for (int j = 0; j < 8; j++) {
            int kk = tk * 8 + j;
            float dist = c2p[kk] - 2.0f * facc[i][j];
            best = min(best, ((u64)f2sort(dist) << 32) | (unsigned)(k0 + kk));
        }
#pragma unroll
        for (int off = 8; off > 0; off >>= 1) {
            u64 o = __shfl_xor(best, off, 16);
            best = min(best, o);
        }
        if (tk == 0 && row < mcnt) {
            int n = order[base + row];
            atomicMin(&keys[n], best);
        }
    }
}

// ------------------------------------------------- gather + residual update -
__global__ void update_kernel(const float* __restrict__ rin, float* __restrict__ resid,
                              const float* __restrict__ cbl, const u64* __restrict__ keys,
                              const int* __restrict__ eid, const float* __restrict__ x,
                              float* __restrict__ out, float* __restrict__ lossacc, int l) {
    int wid = threadIdx.x >> 6, lane = threadIdx.x & 63;
    int n = blockIdx.x * 4 + wid;
    u64 key = keys[n];
    int idx = (int)(key & 0xFFFFFFFFull);
    int e = eid[n];
    const float* qrow = cbl + ((size_t)e * K + idx) * D;
    float4 q4 = *reinterpret_cast<const float4*>(qrow + lane * 4);
    float4 r4 = *reinterpret_cast<const float4*>(rin + (size_t)n * D + lane * 4);
    float dx = q4.x - r4.x, dy = q4.y - r4.y, dz = q4.z - r4.z, dw = q4.w - r4.w;
    float s = dx * dx + dy * dy + dz * dz + dw * dw;
    float4 nr = make_float4(r4.x - q4.x, r4.y - q4.y, r4.z - q4.z, r4.w - q4.w);
    if (l < L - 1) {
        *reinterpret_cast<float4*>(resid + (size_t)n * D + lane * 4) = nr;
    } else {
        // x_q = sum of quants = x - r_final
        float4 x4 = *reinterpret_cast<const float4*>(x + (size_t)n * D + lane * 4);
        float4 xq = make_float4(x4.x - nr.x, x4.y - nr.y, x4.z - nr.z, x4.w - nr.w);
        *reinterpret_cast<float4*>(out + (size_t)n * D + lane * 4) = xq;
    }
#pragma unroll
    for (int off = 32; off > 0; off >>= 1) s += __shfl_xor(s, off);
    if (lane == 0) {
        atomicAdd(lossacc, s);
        out[(size_t)N * D + 1 + (size_t)n * (L + 1) + l] = (float)idx;
    }
}

__global__ void loss_fin_kernel(const float* __restrict__ lossacc, float* __restrict__ out) {
    // mean over levels of [ (1+BETA) * sum_l / (N*D) ], BETA=1
    out[(size_t)N * D] = 2.0f * lossacc[0] / ((float)N * (float)D * (float)L);
}

// ----------------------------------------------------------------------------
extern "C" void kernel_launch(void* const* d_in, const int* in_sizes, int n_in,
                              void* d_out, int out_size, void* d_ws, size_t ws_size,
                              hipStream_t stream) {
    const float* x   = (const float*)d_in[0];
    // d_in[1] = labels (unused by the reference computation)
    const float* cbs = (const float*)d_in[2];
    const float* gW  = (const float*)d_in[3];
    const float* gb  = (const float*)d_in[4];
    float* out = (float*)d_out;

    char* ws = (char*)d_ws;
    float* resid   = (float*)(ws);                                   // 8,388,608 B
    u64*   keys    = (u64*)(ws + 8388608);                           //    65,536 B
    float* c2      = (float*)(ws + 8388608 + 65536);                 //   131,072 B
    int*   eid     = (int*)(ws + 8388608 + 65536 + 131072);          //    32,768 B
    int*   order   = (int*)(ws + 8388608 + 65536 + 131072 + 32768);  //    32,768 B
    char*  smallp  = ws + 8388608 + 65536 + 131072 + 32768 + 32768;
    int*   counts  = (int*)(smallp);           // 32 B
    int*   eoff    = (int*)(smallp + 32);      // 36 B
    int*   cursors = (int*)(smallp + 96);      // 32 B
    float* lossacc = (float*)(smallp + 128);   // 4 B

    // zero counts/eoff/cursors/lossacc in one shot
    hipMemsetAsync(smallp, 0, 160, stream);

    gate_kernel<<<N / 4, 256, 0, stream>>>(x, gW, gb, eid, counts,
                                           out + (size_t)N * D + 1);
    offsets_kernel<<<1, 64, 0, stream>>>(counts, eoff);
    scatter_kernel<<<N / 256, 256, 0, stream>>>(eid, eoff, cursors, order);
    c2_kernel<<<(L * E * K) / 4, 256, 0, stream>>>(cbs, c2);

    for (int l = 0; l < L; l++) {
        hipMemsetAsync(keys, 0xFF, (size_t)N * sizeof(u64), stream);
        const float* rin = (l == 0) ? x : resid;
        const float* cbl = cbs + (size_t)l * E * K * D;
        const float* c2l = c2 + (size_t)l * E * K;
        dist_kernel<<<MAXTILES * KSPLIT, 256, 0, stream>>>(rin, cbl, c2l, order, eoff, keys);
        update_kernel<<<N / 4, 256, 0, stream>>>(rin, resid, cbl, keys, eid, x, out,
                                                 lossacc, l);
    }
    loss_fin_kernel<<<1, 1, 0, stream>>>(lossacc, out);
}

// Round 3
// 742.331 us; speedup vs baseline: 1.5221x; 1.5221x over previous
//
#include <hip/hip_runtime.h>
#include <stdint.h>

#define N 8192
#define D 256
#define L 4
#define K 1024
#define E 8

#define TM 128            // samples per dist block
#define TN 128            // codes per dist block
#define BK 32             // k-chunk (one MFMA k-step)
#define KSPLIT (K / TN)   // 8
#define MAXTILES (N / TM + E)   // 72
#define MARGIN 4e-4f

typedef unsigned long long u64;
typedef __attribute__((ext_vector_type(8))) short bf16x8;
typedef __attribute__((ext_vector_type(4))) float f32x4;

__device__ __forceinline__ unsigned f2sort(float f) {
    unsigned u = __float_as_uint(f);
    return (u & 0x80000000u) ? ~u : (u | 0x80000000u);
}
__device__ __forceinline__ float sort2f(unsigned s) {
    unsigned u = (s & 0x80000000u) ? (s & 0x7fffffffu) : ~s;
    return __uint_as_float(u);
}
__device__ __forceinline__ u64 umin64(u64 a, u64 b) { return a < b ? a : b; }
__device__ __forceinline__ u64 umax64(u64 a, u64 b) { return a > b ? a : b; }

// manual RNE f32->bf16 (finite inputs)
__device__ __forceinline__ unsigned short f2bf(float f) {
    unsigned u = __float_as_uint(f);
    unsigned r = (u + 0x7fffu + ((u >> 16) & 1u)) >> 16;
    return (unsigned short)r;
}
__device__ __forceinline__ float bf2f(unsigned short h) {
    return __uint_as_float(((unsigned)h) << 16);
}

__device__ __forceinline__ void gload_lds16(const void* g, void* l) {
    __builtin_amdgcn_global_load_lds(
        (const __attribute__((address_space(1))) unsigned int*)(g),
        (__attribute__((address_space(3))) unsigned int*)(l), 16, 0, 0);
}

// ------------------------------------------------------------- gate ---------
// wave per sample: logits = x@W + b, expert = argmax; also writes x hi/lo bf16
__global__ void gate_kernel(const float* __restrict__ x,
                            const float* __restrict__ gW,
                            const float* __restrict__ gb,
                            int* __restrict__ eid, int* __restrict__ counts,
                            float* __restrict__ out_idx,
                            unsigned short* __restrict__ rhi,
                            unsigned short* __restrict__ rlo) {
    int wid = threadIdx.x >> 6, lane = threadIdx.x & 63;
    int n = blockIdx.x * 4 + wid;
    float4 xv = *reinterpret_cast<const float4*>(x + (size_t)n * D + lane * 4);

    // bf16 hi/lo split of x (residual for level 0)
    ushort4 h4, l4;
    h4.x = f2bf(xv.x); l4.x = f2bf(xv.x - bf2f(h4.x));
    h4.y = f2bf(xv.y); l4.y = f2bf(xv.y - bf2f(h4.y));
    h4.z = f2bf(xv.z); l4.z = f2bf(xv.z - bf2f(h4.z));
    h4.w = f2bf(xv.w); l4.w = f2bf(xv.w - bf2f(h4.w));
    *reinterpret_cast<ushort4*>(rhi + (size_t)n * D + lane * 4) = h4;
    *reinterpret_cast<ushort4*>(rlo + (size_t)n * D + lane * 4) = l4;

    float xa[4] = {xv.x, xv.y, xv.z, xv.w};
    float a[8];
#pragma unroll
    for (int e = 0; e < 8; e++) a[e] = 0.f;
    const float* wr = gW + (size_t)(lane * 4) * E;
#pragma unroll
    for (int i = 0; i < 4; i++) {
        float xs = xa[i];
        float4 w0 = *reinterpret_cast<const float4*>(wr + i * E);
        float4 w1 = *reinterpret_cast<const float4*>(wr + i * E + 4);
        a[0] = fmaf(xs, w0.x, a[0]); a[1] = fmaf(xs, w0.y, a[1]);
        a[2] = fmaf(xs, w0.z, a[2]); a[3] = fmaf(xs, w0.w, a[3]);
        a[4] = fmaf(xs, w1.x, a[4]); a[5] = fmaf(xs, w1.y, a[5]);
        a[6] = fmaf(xs, w1.z, a[6]); a[7] = fmaf(xs, w1.w, a[7]);
    }
#pragma unroll
    for (int off = 32; off > 0; off >>= 1) {
#pragma unroll
        for (int e = 0; e < 8; e++) a[e] += __shfl_xor(a[e], off);
    }
    if (lane == 0) {
        int be = 0;
        float bv = a[0] + gb[0];
        for (int e = 1; e < 8; e++) {
            float v = a[e] + gb[e];
            if (v > bv) { bv = v; be = e; }
        }
        eid[n] = be;
        out_idx[(size_t)n * (L + 1) + L] = (float)be;
        atomicAdd(&counts[be], 1);
    }
}

// --------------------------------------- codebook prep: c2 + bf16 hi/lo -----
__global__ void cb_prep(const float* __restrict__ cbs, float* __restrict__ c2,
                        unsigned short* __restrict__ cbhi,
                        unsigned short* __restrict__ cblo) {
    int wid = threadIdx.x >> 6, lane = threadIdx.x & 63;
    size_t row = (size_t)blockIdx.x * 4 + wid;   // [0, L*E*K)
    float4 v = *reinterpret_cast<const float4*>(cbs + row * D + lane * 4);
    ushort4 h4, l4;
    h4.x = f2bf(v.x); l4.x = f2bf(v.x - bf2f(h4.x));
    h4.y = f2bf(v.y); l4.y = f2bf(v.y - bf2f(h4.y));
    h4.z = f2bf(v.z); l4.z = f2bf(v.z - bf2f(h4.z));
    h4.w = f2bf(v.w); l4.w = f2bf(v.w - bf2f(h4.w));
    *reinterpret_cast<ushort4*>(cbhi + row * D + lane * 4) = h4;
    *reinterpret_cast<ushort4*>(cblo + row * D + lane * 4) = l4;
    float s = v.x * v.x + v.y * v.y + v.z * v.z + v.w * v.w;
#pragma unroll
    for (int off = 32; off > 0; off >>= 1) s += __shfl_xor(s, off);
    if (lane == 0) c2[row] = s;
}

// ------------------------------------ bucket by expert (inline offsets) -----
__global__ void scatter_kernel(const int* __restrict__ eid,
                               const int* __restrict__ counts,
                               int* __restrict__ cursors, int* __restrict__ order) {
    int off[E]; int a = 0;
#pragma unroll
    for (int e = 0; e < E; e++) { off[e] = a; a += counts[e]; }
    int n = blockIdx.x * 256 + threadIdx.x;
    int e = eid[n];
    int pos = atomicAdd(&cursors[e], 1);
    order[off[e] + pos] = n;
}

// ------------------------------------------------------------ distances -----
// 128x128 tile, bf16x3 MFMA (hi*hi + hi*lo + lo*hi), exact fp32 c2.
// LDS row layout: [row][ hi d0..31 | lo d0..31 ], 16B chunks XOR-swizzled by row&7.
// Writes per-sample (best,second) for this 128-code chunk (split by wave col).
__global__ __launch_bounds__(256, 3)
void dist_kernel(const unsigned short* __restrict__ rhi,
                 const unsigned short* __restrict__ rlo,
                 const unsigned short* __restrict__ cbhi,
                 const unsigned short* __restrict__ cblo,
                 const float* __restrict__ c2l,
                 const int* __restrict__ order, const int* __restrict__ counts,
                 uint4* __restrict__ ws2) {
    int bx = blockIdx.x;
    int tile = bx >> 3, kc = bx & 7;

    int eoffL[E + 1]; int a = 0;
#pragma unroll
    for (int i = 0; i < E; i++) { eoffL[i] = a; a += counts[i]; }
    eoffL[E] = a;

    int e = -1, lt = 0, cnt = 0, cum = 0;
    for (int i = 0; i < E; i++) {
        int c = counts[i];
        int t = (c + TM - 1) / TM;
        if (tile < cum + t) { e = i; lt = tile - cum; cnt = c; break; }
        cum += t;
    }
    if (e < 0) return;
    int base = eoffL[e] + lt * TM;
    int mcnt = min(TM, cnt - lt * TM);
    int k0 = kc * TN;

    __shared__ short lA[TM * 64];
    __shared__ short lB[TN * 64];

    int tid = threadIdx.x;
    int lane = tid & 63, wv = tid >> 6;
    int wr = wv >> 1, wc = wv & 1;

    f32x4 acc[4][4];
#pragma unroll
    for (int fr = 0; fr < 4; fr++)
#pragma unroll
        for (int fc = 0; fc < 4; fc++)
            acc[fr][fc] = (f32x4){0.f, 0.f, 0.f, 0.f};

    const size_t cbbase = ((size_t)e * K + k0) * D;

    for (int ck = 0; ck < D / BK; ck++) {
        int dc = ck * BK;
        __syncthreads();
        // stage A (samples): pre-swizzled per-lane global source, linear LDS dest
#pragma unroll
        for (int i = 0; i < 4; i++) {
            int s = i * 256 + tid;
            int row = s >> 3, cs = s & 7, c = cs ^ (row & 7);
            int nidx = order[min(base + row, N - 1)];
            const unsigned short* src = (c < 4)
                ? (rhi + (size_t)nidx * D + dc + c * 8)
                : (rlo + (size_t)nidx * D + dc + (c - 4) * 8);
            gload_lds16(src, &lA[s * 8]);
        }
        // stage B (codes)
#pragma unroll
        for (int i = 0; i < 4; i++) {
            int s = i * 256 + tid;
            int row = s >> 3, cs = s & 7, c = cs ^ (row & 7);
            const unsigned short* src = (c < 4)
                ? (cbhi + cbbase + (size_t)row * D + dc + c * 8)
                : (cblo + cbbase + (size_t)row * D + dc + (c - 4) * 8);
            gload_lds16(src, &lB[s * 8]);
        }
        __syncthreads();

        bf16x8 ah[4], al[4];
        int q = lane >> 4, rL = lane & 15;
#pragma unroll
        for (int fr = 0; fr < 4; fr++) {
            int row = wr * 64 + fr * 16 + rL;
            ah[fr] = *reinterpret_cast<const bf16x8*>(&lA[row * 64 + ((q) ^ (row & 7)) * 8]);
            al[fr] = *reinterpret_cast<const bf16x8*>(&lA[row * 64 + ((4 + q) ^ (row & 7)) * 8]);
        }
#pragma unroll
        for (int fc = 0; fc < 4; fc++) {
            int row = wc * 64 + fc * 16 + rL;
            bf16x8 bh = *reinterpret_cast<const bf16x8*>(&lB[row * 64 + ((q) ^ (row & 7)) * 8]);
            bf16x8 bl = *reinterpret_cast<const bf16x8*>(&lB[row * 64 + ((4 + q) ^ (row & 7)) * 8]);
#pragma unroll
            for (int fr = 0; fr < 4; fr++) {
                acc[fr][fc] = __builtin_amdgcn_mfma_f32_16x16x32_bf16(ah[fr], bh, acc[fr][fc], 0, 0, 0);
                acc[fr][fc] = __builtin_amdgcn_mfma_f32_16x16x32_bf16(ah[fr], bl, acc[fr][fc], 0, 0, 0);
                acc[fr][fc] = __builtin_amdgcn_mfma_f32_16x16x32_bf16(al[fr], bh, acc[fr][fc], 0, 0, 0);
            }
        }
    }

    // epilogue: dist = c2 - 2*dot; per-row (best,second) over this block's cols
    int q = lane >> 4, cL = lane & 15;
#pragma unroll
    for (int fr = 0; fr < 4; fr++) {
#pragma unroll
        for (int j = 0; j < 4; j++) {
            int row_local = wr * 64 + fr * 16 + q * 4 + j;
            u64 best = ~0ull; unsigned sec = 0xFFFFFFFFu;
#pragma unroll
            for (int fc = 0; fc < 4; fc++) {
                int col = k0 + wc * 64 + fc * 16 + cL;
                float dist = c2l[e * K + col] - 2.0f * acc[fr][fc][j];
                u64 kk = ((u64)f2sort(dist) << 32) | (unsigned)col;
                u64 mx = umax64(best, kk);
                best = umin64(best, kk);
                sec = min(sec, (unsigned)(mx >> 32));
            }
#pragma unroll
            for (int m = 1; m < 16; m <<= 1) {
                u64 ob = __shfl_xor(best, m, 16);
                unsigned os = __shfl_xor(sec, m, 16);
                u64 mx = umax64(best, ob);
                best = umin64(best, ob);
                sec = min(min(sec, os), (unsigned)(mx >> 32));
            }
            if (cL == 0 && row_local < mcnt) {
                int n = order[base + row_local];
                uint4 v;
                v.x = (unsigned)(best & 0xffffffffu);
                v.y = (unsigned)(best >> 32);
                v.z = sec; v.w = 0;
                ws2[(size_t)n * 16 + kc * 2 + wc] = v;
            }
        }
    }
}

// ------------------- resolve + (rare) exact fp32 rescore + residual update --
__global__ __launch_bounds__(256)
void update_kernel(const float* __restrict__ rin, float* __restrict__ resid,
                   const float* __restrict__ cbl, const uint4* __restrict__ ws2,
                   const int* __restrict__ eid, const float* __restrict__ x,
                   float* __restrict__ out, float* __restrict__ lossacc,
                   const float* __restrict__ c2l,
                   unsigned short* __restrict__ rhi, unsigned short* __restrict__ rlo,
                   int l) {
    __shared__ float sh[4][D];
    __shared__ float lsum[4];
    int wid = threadIdx.x >> 6, lane = threadIdx.x & 63;
    int n = blockIdx.x * 4 + wid;
    int e = eid[n];

    float4 r4 = *reinterpret_cast<const float4*>(rin + (size_t)n * D + lane * 4);
    *reinterpret_cast<float4*>(&sh[wid][lane * 4]) = r4;

    // resolve global best/second from the 16 chunk entries
    uint4 ev = ws2[(size_t)n * 16 + (lane & 15)];
    u64 best = ((u64)ev.y << 32) | ev.x;
    unsigned sec = ev.z;
#pragma unroll
    for (int m = 1; m < 16; m <<= 1) {
        u64 ob = __shfl_xor(best, m, 16);
        unsigned os = __shfl_xor(sec, m, 16);
        u64 mx = umax64(best, ob);
        best = umin64(best, ob);
        sec = min(min(sec, os), (unsigned)(mx >> 32));
    }
    float bd = sort2f((unsigned)(best >> 32));
    float sd = sort2f(sec);
    int idx = (int)(best & 0xffffffffu);

    if (sd - bd < MARGIN) {
        // exact fp32 rescore over all K codes of this sample's expert
        u64 rb = ~0ull;
        const float* cbe = cbl + (size_t)e * K * D;
        for (int t = 0; t < K / 64; t++) {
            int k = t * 64 + lane;
            const float* crow = cbe + (size_t)k * D;
            float dot = 0.f;
            for (int d0 = 0; d0 < D; d0 += 4) {
                float4 c4 = *reinterpret_cast<const float4*>(crow + d0);
                float4 s4 = *reinterpret_cast<const float4*>(&sh[wid][d0]);
                dot = fmaf(s4.x, c4.x, dot);
                dot = fmaf(s4.y, c4.y, dot);
                dot = fmaf(s4.z, c4.z, dot);
                dot = fmaf(s4.w, c4.w, dot);
            }
            float dist = c2l[e * K + k] - 2.0f * dot;
            rb = umin64(rb, ((u64)f2sort(dist) << 32) | (unsigned)k);
        }
#pragma unroll
        for (int m = 1; m < 64; m <<= 1) rb = umin64(rb, __shfl_xor(rb, m));
        idx = (int)(rb & 0xffffffffu);
    }

    // gather chosen code row, update residual, loss, next-level bf16
    const float* qrow = cbl + ((size_t)e * K + idx) * D;
    float4 q4 = *reinterpret_cast<const float4*>(qrow + lane * 4);
    float dx = q4.x - r4.x, dy = q4.y - r4.y, dz = q4.z - r4.z, dw = q4.w - r4.w;
    float s = dx * dx + dy * dy + dz * dz + dw * dw;
    float4 nr = make_float4(r4.x - q4.x, r4.y - q4.y, r4.z - q4.z, r4.w - q4.w);
    if (l < L - 1) {
        *reinterpret_cast<float4*>(resid + (size_t)n * D + lane * 4) = nr;
        ushort4 h4, l4w;
        h4.x = f2bf(nr.x); l4w.x = f2bf(nr.x - bf2f(h4.x));
        h4.y = f2bf(nr.y); l4w.y = f2bf(nr.y - bf2f(h4.y));
        h4.z = f2bf(nr.z); l4w.z = f2bf(nr.z - bf2f(h4.z));
        h4.w = f2bf(nr.w); l4w.w = f2bf(nr.w - bf2f(h4.w));
        *reinterpret_cast<ushort4*>(rhi + (size_t)n * D + lane * 4) = h4;
        *reinterpret_cast<ushort4*>(rlo + (size_t)n * D + lane * 4) = l4w;
    } else {
        float4 x4 = *reinterpret_cast<const float4*>(x + (size_t)n * D + lane * 4);
        float4 xq = make_float4(x4.x - nr.x, x4.y - nr.y, x4.z - nr.z, x4.w - nr.w);
        *reinterpret_cast<float4*>(out + (size_t)n * D + lane * 4) = xq;
    }
#pragma unroll
    for (int off = 32; off > 0; off >>= 1) s += __shfl_xor(s, off);
    if (lane == 0) {
        lsum[wid] = s;
        out[(size_t)N * D + 1 + (size_t)n * (L + 1) + l] = (float)idx;
    }
    __syncthreads();
    if (threadIdx.x == 0) {
        atomicAdd(lossacc, lsum[0] + lsum[1] + lsum[2] + lsum[3]);
    }
}

__global__ void loss_fin_kernel(const float* __restrict__ lossacc, float* __restrict__ out) {
    out[(size_t)N * D] = 2.0f * lossacc[0] / ((float)N * (float)D * (float)L);
}

// ----------------------------------------------------------------------------
extern "C" void kernel_launch(void* const* d_in, const int* in_sizes, int n_in,
                              void* d_out, int out_size, void* d_ws, size_t ws_size,
                              hipStream_t stream) {
    const float* x   = (const float*)d_in[0];
    // d_in[1] = labels (unused)
    const float* cbs = (const float*)d_in[2];
    const float* gW  = (const float*)d_in[3];
    const float* gb  = (const float*)d_in[4];
    float* out = (float*)d_out;

    char* ws = (char*)d_ws;
    float*          resid = (float*)(ws);                       //  8,388,608
    unsigned short* rhi   = (unsigned short*)(ws + 8388608);    //  4,194,304
    unsigned short* rlo   = (unsigned short*)(ws + 12582912);   //  4,194,304
    unsigned short* cbhi  = (unsigned short*)(ws + 16777216);   // 16,777,216
    unsigned short* cblo  = (unsigned short*)(ws + 33554432);   // 16,777,216
    float*          c2    = (float*)(ws + 50331648);            //    131,072
    int*            eid   = (int*)(ws + 50462720);              //     32,768
    int*            order = (int*)(ws + 50495488);              //     33,280 (pad)
    uint4*          ws2   = (uint4*)(ws + 50528768);            //  2,097,152
    char*           smallp = ws + 52625920;
    int*   counts  = (int*)(smallp);          // 32 B
    int*   cursors = (int*)(smallp + 64);     // 32 B
    float* lossacc = (float*)(smallp + 128);  // 4 B

    hipMemsetAsync(smallp, 0, 192, stream);

    gate_kernel<<<N / 4, 256, 0, stream>>>(x, gW, gb, eid, counts,
                                           out + (size_t)N * D + 1, rhi, rlo);
    cb_prep<<<(L * E * K) / 4, 256, 0, stream>>>(cbs, c2, cbhi, cblo);
    scatter_kernel<<<N / 256, 256, 0, stream>>>(eid, counts, cursors, order);

    for (int l = 0; l < L; l++) {
        const float* rin = (l == 0) ? x : resid;
        size_t cboff = (size_t)l * E * K * D;
        const float* c2l = c2 + (size_t)l * E * K;
        dist_kernel<<<MAXTILES * KSPLIT, 256, 0, stream>>>(
            rhi, rlo, cbhi + cboff, cblo + cboff, c2l, order, counts, ws2);
        update_kernel<<<N / 4, 256, 0, stream>>>(
            rin, resid, cbs + cboff, ws2, eid, x, out, lossacc, c2l, rhi, rlo, l);
    }
    loss_fin_kernel<<<1, 1, 0, stream>>>(lossacc, out);
}

// Round 4
// 607.377 us; speedup vs baseline: 1.8604x; 1.2222x over previous
//
#include <hip/hip_runtime.h>
#include <stdint.h>

#define N 8192
#define D 256
#define L 4
#define K 1024
#define E 8

#define TM 128            // samples per dist block
#define TN 128            // codes per dist block
#define BK 32             // k-chunk (one MFMA k-step)
#define KSPLIT (K / TN)   // 8
#define MAXTILES (N / TM + E)   // 72
#define MARGIN 4e-4f

typedef unsigned long long u64;
typedef __attribute__((ext_vector_type(8))) short bf16x8;
typedef __attribute__((ext_vector_type(4))) float f32x4;

__device__ __forceinline__ unsigned f2sort(float f) {
    unsigned u = __float_as_uint(f);
    return (u & 0x80000000u) ? ~u : (u | 0x80000000u);
}
__device__ __forceinline__ float sort2f(unsigned s) {
    unsigned u = (s & 0x80000000u) ? (s & 0x7fffffffu) : ~s;
    return __uint_as_float(u);
}
__device__ __forceinline__ u64 umin64(u64 a, u64 b) { return a < b ? a : b; }
__device__ __forceinline__ u64 umax64(u64 a, u64 b) { return a > b ? a : b; }

// manual RNE f32->bf16 (finite inputs)
__device__ __forceinline__ unsigned short f2bf(float f) {
    unsigned u = __float_as_uint(f);
    unsigned r = (u + 0x7fffu + ((u >> 16) & 1u)) >> 16;
    return (unsigned short)r;
}
__device__ __forceinline__ float bf2f(unsigned short h) {
    return __uint_as_float(((unsigned)h) << 16);
}

__device__ __forceinline__ void gload_lds16(const void* g, void* l) {
    __builtin_amdgcn_global_load_lds(
        (const __attribute__((address_space(1))) unsigned int*)(g),
        (__attribute__((address_space(3))) unsigned int*)(l), 16, 0, 0);
}

// ------------------------------------------------------------- gate ---------
__global__ void gate_kernel(const float* __restrict__ x,
                            const float* __restrict__ gW,
                            const float* __restrict__ gb,
                            int* __restrict__ eid, int* __restrict__ counts,
                            float* __restrict__ out_idx,
                            unsigned short* __restrict__ rhi,
                            unsigned short* __restrict__ rlo) {
    int wid = threadIdx.x >> 6, lane = threadIdx.x & 63;
    int n = blockIdx.x * 4 + wid;
    float4 xv = *reinterpret_cast<const float4*>(x + (size_t)n * D + lane * 4);

    ushort4 h4, l4;
    h4.x = f2bf(xv.x); l4.x = f2bf(xv.x - bf2f(h4.x));
    h4.y = f2bf(xv.y); l4.y = f2bf(xv.y - bf2f(h4.y));
    h4.z = f2bf(xv.z); l4.z = f2bf(xv.z - bf2f(h4.z));
    h4.w = f2bf(xv.w); l4.w = f2bf(xv.w - bf2f(h4.w));
    *reinterpret_cast<ushort4*>(rhi + (size_t)n * D + lane * 4) = h4;
    *reinterpret_cast<ushort4*>(rlo + (size_t)n * D + lane * 4) = l4;

    float xa[4] = {xv.x, xv.y, xv.z, xv.w};
    float a[8];
#pragma unroll
    for (int e = 0; e < 8; e++) a[e] = 0.f;
    const float* wr = gW + (size_t)(lane * 4) * E;
#pragma unroll
    for (int i = 0; i < 4; i++) {
        float xs = xa[i];
        float4 w0 = *reinterpret_cast<const float4*>(wr + i * E);
        float4 w1 = *reinterpret_cast<const float4*>(wr + i * E + 4);
        a[0] = fmaf(xs, w0.x, a[0]); a[1] = fmaf(xs, w0.y, a[1]);
        a[2] = fmaf(xs, w0.z, a[2]); a[3] = fmaf(xs, w0.w, a[3]);
        a[4] = fmaf(xs, w1.x, a[4]); a[5] = fmaf(xs, w1.y, a[5]);
        a[6] = fmaf(xs, w1.z, a[6]); a[7] = fmaf(xs, w1.w, a[7]);
    }
#pragma unroll
    for (int off = 32; off > 0; off >>= 1) {
#pragma unroll
        for (int e = 0; e < 8; e++) a[e] += __shfl_xor(a[e], off);
    }
    if (lane == 0) {
        int be = 0;
        float bv = a[0] + gb[0];
        for (int e = 1; e < 8; e++) {
            float v = a[e] + gb[e];
            if (v > bv) { bv = v; be = e; }
        }
        eid[n] = be;
        out_idx[(size_t)n * (L + 1) + L] = (float)be;
        atomicAdd(&counts[be], 1);
    }
}

// --------------------------------------- codebook prep: c2 + bf16 hi/lo -----
__global__ void cb_prep(const float* __restrict__ cbs, float* __restrict__ c2,
                        unsigned short* __restrict__ cbhi,
                        unsigned short* __restrict__ cblo) {
    int wid = threadIdx.x >> 6, lane = threadIdx.x & 63;
    size_t row = (size_t)blockIdx.x * 4 + wid;
    float4 v = *reinterpret_cast<const float4*>(cbs + row * D + lane * 4);
    ushort4 h4, l4;
    h4.x = f2bf(v.x); l4.x = f2bf(v.x - bf2f(h4.x));
    h4.y = f2bf(v.y); l4.y = f2bf(v.y - bf2f(h4.y));
    h4.z = f2bf(v.z); l4.z = f2bf(v.z - bf2f(h4.z));
    h4.w = f2bf(v.w); l4.w = f2bf(v.w - bf2f(h4.w));
    *reinterpret_cast<ushort4*>(cbhi + row * D + lane * 4) = h4;
    *reinterpret_cast<ushort4*>(cblo + row * D + lane * 4) = l4;
    float s = v.x * v.x + v.y * v.y + v.z * v.z + v.w * v.w;
#pragma unroll
    for (int off = 32; off > 0; off >>= 1) s += __shfl_xor(s, off);
    if (lane == 0) c2[row] = s;
}

// ------------------------------------ bucket by expert ----------------------
__global__ void scatter_kernel(const int* __restrict__ eid,
                               const int* __restrict__ counts,
                               int* __restrict__ cursors, int* __restrict__ order) {
    int off[E]; int a = 0;
#pragma unroll
    for (int e = 0; e < E; e++) { off[e] = a; a += counts[e]; }
    int n = blockIdx.x * 256 + threadIdx.x;
    int e = eid[n];
    int pos = atomicAdd(&cursors[e], 1);
    order[off[e] + pos] = n;
}

// ------------------------------------------------------------ distances -----
// 128x128 tile, bf16x3 MFMA, double-buffered LDS (stage k+1 overlaps MFMA k),
// one barrier per chunk. Writes per-sample (best,second) per 64-code half.
__global__ __launch_bounds__(256, 2)
void dist_kernel(const unsigned short* __restrict__ rhi,
                 const unsigned short* __restrict__ rlo,
                 const unsigned short* __restrict__ cbhi,
                 const unsigned short* __restrict__ cblo,
                 const float* __restrict__ c2l,
                 const int* __restrict__ order, const int* __restrict__ counts,
                 uint4* __restrict__ ws2) {
    __shared__ short lA[2][TM * 64];
    __shared__ short lB[2][TN * 64];

    int bx = blockIdx.x;
    int tile = bx >> 3, kc = bx & 7;

    int eoffL[E + 1]; int a = 0;
#pragma unroll
    for (int i = 0; i < E; i++) { eoffL[i] = a; a += counts[i]; }
    eoffL[E] = a;

    int e = -1, lt = 0, cnt = 0, cum = 0;
    for (int i = 0; i < E; i++) {
        int c = counts[i];
        int t = (c + TM - 1) / TM;
        if (tile < cum + t) { e = i; lt = tile - cum; cnt = c; break; }
        cum += t;
    }
    if (e < 0) return;
    int base = eoffL[e] + lt * TM;
    int mcnt = min(TM, cnt - lt * TM);
    int k0 = kc * TN;

    int tid = threadIdx.x;
    int lane = tid & 63, wv = tid >> 6;
    int wr = wv >> 1, wc = wv & 1;

    // hoisted per-thread staging addresses (row/col fixed across chunks)
    int srow[4], scol[4], nid[4];
#pragma unroll
    for (int i = 0; i < 4; i++) {
        int s = i * 256 + tid;
        srow[i] = s >> 3;
        scol[i] = (s & 7) ^ (srow[i] & 7);
        nid[i] = 0;
    }
#pragma unroll
    for (int i = 0; i < 4; i++) nid[i] = order[min(base + srow[i], N - 1)];

    const size_t cbbase = ((size_t)e * K + k0) * D;

    f32x4 acc[4][4];
#pragma unroll
    for (int fr = 0; fr < 4; fr++)
#pragma unroll
        for (int fc = 0; fc < 4; fc++)
            acc[fr][fc] = (f32x4){0.f, 0.f, 0.f, 0.f};

    auto STAGE = [&](int buf, int ck) {
        int dc = ck * BK;
#pragma unroll
        for (int i = 0; i < 4; i++) {
            int s = i * 256 + tid, c = scol[i];
            const unsigned short* src = (c < 4)
                ? (rhi + (size_t)nid[i] * D + dc + c * 8)
                : (rlo + (size_t)nid[i] * D + dc + (c - 4) * 8);
            gload_lds16(src, &lA[buf][s * 8]);
        }
#pragma unroll
        for (int i = 0; i < 4; i++) {
            int s = i * 256 + tid, c = scol[i];
            const unsigned short* src = (c < 4)
                ? (cbhi + cbbase + (size_t)srow[i] * D + dc + c * 8)
                : (cblo + cbbase + (size_t)srow[i] * D + dc + (c - 4) * 8);
            gload_lds16(src, &lB[buf][s * 8]);
        }
    };

    int q = lane >> 4, rL = lane & 15;
    STAGE(0, 0);
    for (int ck = 0; ck < D / BK; ck++) {
        __syncthreads();              // drains vmcnt for stage(ck), syncs block
        if (ck < D / BK - 1) STAGE((ck + 1) & 1, ck + 1);
        int buf = ck & 1;
        bf16x8 ah[4], al[4];
#pragma unroll
        for (int fr = 0; fr < 4; fr++) {
            int row = wr * 64 + fr * 16 + rL;
            ah[fr] = *reinterpret_cast<const bf16x8*>(&lA[buf][row * 64 + ((q) ^ (row & 7)) * 8]);
            al[fr] = *reinterpret_cast<const bf16x8*>(&lA[buf][row * 64 + ((4 + q) ^ (row & 7)) * 8]);
        }
#pragma unroll
        for (int fc = 0; fc < 4; fc++) {
            int row = wc * 64 + fc * 16 + rL;
            bf16x8 bh = *reinterpret_cast<const bf16x8*>(&lB[buf][row * 64 + ((q) ^ (row & 7)) * 8]);
            bf16x8 bl = *reinterpret_cast<const bf16x8*>(&lB[buf][row * 64 + ((4 + q) ^ (row & 7)) * 8]);
#pragma unroll
            for (int fr = 0; fr < 4; fr++) {
                acc[fr][fc] = __builtin_amdgcn_mfma_f32_16x16x32_bf16(ah[fr], bh, acc[fr][fc], 0, 0, 0);
                acc[fr][fc] = __builtin_amdgcn_mfma_f32_16x16x32_bf16(ah[fr], bl, acc[fr][fc], 0, 0, 0);
                acc[fr][fc] = __builtin_amdgcn_mfma_f32_16x16x32_bf16(al[fr], bh, acc[fr][fc], 0, 0, 0);
            }
        }
    }

    // epilogue: dist = c2 - 2*dot; per-row (best,second) over this block's cols
    int cL = lane & 15;
#pragma unroll
    for (int fr = 0; fr < 4; fr++) {
#pragma unroll
        for (int j = 0; j < 4; j++) {
            int row_local = wr * 64 + fr * 16 + q * 4 + j;
            u64 best = ~0ull; unsigned sec = 0xFFFFFFFFu;
#pragma unroll
            for (int fc = 0; fc < 4; fc++) {
                int col = k0 + wc * 64 + fc * 16 + cL;
                float dist = c2l[e * K + col] - 2.0f * acc[fr][fc][j];
                u64 kk = ((u64)f2sort(dist) << 32) | (unsigned)col;
                u64 mx = umax64(best, kk);
                best = umin64(best, kk);
                sec = min(sec, (unsigned)(mx >> 32));
            }
#pragma unroll
            for (int m = 1; m < 16; m <<= 1) {
                u64 ob = __shfl_xor(best, m, 16);
                unsigned os = __shfl_xor(sec, m, 16);
                u64 mx = umax64(best, ob);
                best = umin64(best, ob);
                sec = min(min(sec, os), (unsigned)(mx >> 32));
            }
            if (cL == 0 && row_local < mcnt) {
                int n = order[base + row_local];
                uint4 v;
                v.x = (unsigned)(best & 0xffffffffu);
                v.y = (unsigned)(best >> 32);
                v.z = sec; v.w = 0;
                ws2[(size_t)n * 16 + kc * 2 + wc] = v;
            }
        }
    }
}

// ---------------- resolve + block-cooperative exact rescore + update --------
// 256 blocks x 32 samples. Phase A: resolve best/second from 16 chunk entries.
// Phase B: rare exact fp32 rescan (whole block, 4 codes/thread). Phase C:
// streaming residual/x_q/loss update.
__global__ __launch_bounds__(256)
void finalize_kernel(const float* __restrict__ rin, float* __restrict__ resid,
                     const float* __restrict__ cbl, const uint4* __restrict__ ws2,
                     const int* __restrict__ eid, const float* __restrict__ x,
                     float* __restrict__ out, float* __restrict__ lossb,
                     const float* __restrict__ c2l,
                     unsigned short* __restrict__ rhi,
                     unsigned short* __restrict__ rlo, int l) {
    __shared__ int s_idx[32];
    __shared__ int s_eid[32];
    __shared__ int s_flag[32];
    __shared__ int s_fcount;
    __shared__ u64 s_rb[4];
    __shared__ float s_ls[4];

    int tid = threadIdx.x, lane = tid & 63, wv = tid >> 6;
    int n0 = blockIdx.x * 32;
    if (tid == 0) s_fcount = 0;
    __syncthreads();

    // ---- phase A: resolve (16 lanes per sample, 4 samples/wave, 2 passes)
#pragma unroll
    for (int pass = 0; pass < 2; pass++) {
        int sloc = wv * 8 + pass * 4 + (lane >> 4);
        int n = n0 + sloc;
        int l16 = lane & 15;
        uint4 ev = ws2[(size_t)n * 16 + l16];
        u64 best = ((u64)ev.y << 32) | ev.x;
        unsigned sec = ev.z;
#pragma unroll
        for (int m = 1; m < 16; m <<= 1) {
            u64 ob = __shfl_xor(best, m, 16);
            unsigned os = __shfl_xor(sec, m, 16);
            u64 mx = umax64(best, ob);
            best = umin64(best, ob);
            sec = min(min(sec, os), (unsigned)(mx >> 32));
        }
        if (l16 == 0) {
            s_idx[sloc] = (int)(best & 0xffffffffu);
            s_eid[sloc] = eid[n];
            float bd = sort2f((unsigned)(best >> 32));
            float sd = sort2f(sec);
            if (sd - bd < MARGIN) {
                int p = atomicAdd(&s_fcount, 1);
                s_flag[p] = sloc;
            }
        }
    }
    __syncthreads();
    int fc = s_fcount;

    // ---- phase B: exact rescore of flagged samples (rare)
    for (int f = 0; f < fc; f++) {
        int sloc = s_flag[f];
        int n = n0 + sloc, e = s_eid[sloc];
        const float* rrow = rin + (size_t)n * D;
        u64 rb = ~0ull;
        for (int c = 0; c < 4; c++) {
            int k = c * 256 + tid;
            const float* crow = cbl + ((size_t)e * K + k) * D;
            float dot = 0.f;
#pragma unroll
            for (int d0 = 0; d0 < D; d0 += 4) {
                float4 c4 = *reinterpret_cast<const float4*>(crow + d0);
                float4 s4 = *reinterpret_cast<const float4*>(rrow + d0);
                dot = fmaf(s4.x, c4.x, dot);
                dot = fmaf(s4.y, c4.y, dot);
                dot = fmaf(s4.z, c4.z, dot);
                dot = fmaf(s4.w, c4.w, dot);
            }
            float dist = c2l[e * K + k] - 2.0f * dot;
            rb = umin64(rb, ((u64)f2sort(dist) << 32) | (unsigned)k);
        }
#pragma unroll
        for (int m = 1; m < 64; m <<= 1) rb = umin64(rb, __shfl_xor(rb, m));
        if (lane == 0) s_rb[wv] = rb;
        __syncthreads();
        if (tid == 0) {
            rb = umin64(umin64(s_rb[0], s_rb[1]), umin64(s_rb[2], s_rb[3]));
            s_idx[sloc] = (int)(rb & 0xffffffffu);
        }
        __syncthreads();
    }

    // ---- phase C: streaming update (32 samples x 64 float4-chunks)
    float lsum = 0.f;
#pragma unroll
    for (int i = 0; i < 8; i++) {
        int c = i * 256 + tid;          // [0, 2048)
        int sloc = c >> 6, f4p = c & 63;
        int n = n0 + sloc;
        int e = s_eid[sloc], idx = s_idx[sloc];
        const float* qrow = cbl + ((size_t)e * K + idx) * D;
        float4 q4 = *reinterpret_cast<const float4*>(qrow + f4p * 4);
        float4 r4 = *reinterpret_cast<const float4*>(rin + (size_t)n * D + f4p * 4);
        float dx = q4.x - r4.x, dy = q4.y - r4.y, dz = q4.z - r4.z, dw = q4.w - r4.w;
        lsum += dx * dx + dy * dy + dz * dz + dw * dw;
        float4 nr = make_float4(r4.x - q4.x, r4.y - q4.y, r4.z - q4.z, r4.w - q4.w);
        if (l < L - 1) {
            *reinterpret_cast<float4*>(resid + (size_t)n * D + f4p * 4) = nr;
            ushort4 h4, l4w;
            h4.x = f2bf(nr.x); l4w.x = f2bf(nr.x - bf2f(h4.x));
            h4.y = f2bf(nr.y); l4w.y = f2bf(nr.y - bf2f(h4.y));
            h4.z = f2bf(nr.z); l4w.z = f2bf(nr.z - bf2f(h4.z));
            h4.w = f2bf(nr.w); l4w.w = f2bf(nr.w - bf2f(h4.w));
            *reinterpret_cast<ushort4*>(rhi + (size_t)n * D + f4p * 4) = h4;
            *reinterpret_cast<ushort4*>(rlo + (size_t)n * D + f4p * 4) = l4w;
        } else {
            float4 x4 = *reinterpret_cast<const float4*>(x + (size_t)n * D + f4p * 4);
            float4 xq = make_float4(x4.x - nr.x, x4.y - nr.y, x4.z - nr.z, x4.w - nr.w);
            *reinterpret_cast<float4*>(out + (size_t)n * D + f4p * 4) = xq;
        }
        if (f4p == 0)
            out[(size_t)N * D + 1 + (size_t)n * (L + 1) + l] = (float)idx;
    }
#pragma unroll
    for (int m = 1; m < 64; m <<= 1) lsum += __shfl_xor(lsum, m);
    if (lane == 0) s_ls[wv] = lsum;
    __syncthreads();
    if (tid == 0)
        atomicAdd(&lossb[blockIdx.x & 31], s_ls[0] + s_ls[1] + s_ls[2] + s_ls[3]);
}

__global__ void loss_fin_kernel(const float* __restrict__ lossb, float* __restrict__ out) {
    float s = 0.f;
    for (int i = 0; i < 32; i++) s += lossb[i];
    out[(size_t)N * D] = 2.0f * s / ((float)N * (float)D * (float)L);
}

// ----------------------------------------------------------------------------
extern "C" void kernel_launch(void* const* d_in, const int* in_sizes, int n_in,
                              void* d_out, int out_size, void* d_ws, size_t ws_size,
                              hipStream_t stream) {
    const float* x   = (const float*)d_in[0];
    // d_in[1] = labels (unused)
    const float* cbs = (const float*)d_in[2];
    const float* gW  = (const float*)d_in[3];
    const float* gb  = (const float*)d_in[4];
    float* out = (float*)d_out;

    char* ws = (char*)d_ws;
    float*          resid = (float*)(ws);                       //  8,388,608
    unsigned short* rhi   = (unsigned short*)(ws + 8388608);    //  4,194,304
    unsigned short* rlo   = (unsigned short*)(ws + 12582912);   //  4,194,304
    unsigned short* cbhi  = (unsigned short*)(ws + 16777216);   // 16,777,216
    unsigned short* cblo  = (unsigned short*)(ws + 33554432);   // 16,777,216
    float*          c2    = (float*)(ws + 50331648);            //    131,072
    int*            eid   = (int*)(ws + 50462720);              //     32,768
    int*            order = (int*)(ws + 50495488);              //     33,280
    uint4*          ws2   = (uint4*)(ws + 50528768);            //  2,097,152
    char*           smallp = ws + 52625920;
    int*   counts  = (int*)(smallp);          // 32 B
    int*   cursors = (int*)(smallp + 64);     // 32 B
    float* lossb   = (float*)(smallp + 128);  // 128 B (32 buckets)

    hipMemsetAsync(smallp, 0, 256, stream);

    gate_kernel<<<N / 4, 256, 0, stream>>>(x, gW, gb, eid, counts,
                                           out + (size_t)N * D + 1, rhi, rlo);
    cb_prep<<<(L * E * K) / 4, 256, 0, stream>>>(cbs, c2, cbhi, cblo);
    scatter_kernel<<<N / 256, 256, 0, stream>>>(eid, counts, cursors, order);

    for (int l = 0; l < L; l++) {
        const float* rin = (l == 0) ? x : resid;
        size_t cboff = (size_t)l * E * K * D;
        const float* c2l = c2 + (size_t)l * E * K;
        dist_kernel<<<MAXTILES * KSPLIT, 256, 0, stream>>>(
            rhi, rlo, cbhi + cboff, cblo + cboff, c2l, order, counts, ws2);
        finalize_kernel<<<N / 32, 256, 0, stream>>>(
            rin, resid, cbs + cboff, ws2, eid, x, out, lossb, c2l, rhi, rlo, l);
    }
    loss_fin_kernel<<<1, 1, 0, stream>>>(lossb, out);
}

// Round 5
// 497.077 us; speedup vs baseline: 2.2732x; 1.2219x over previous
//
#include <hip/hip_runtime.h>
#include <stdint.h>

#define N 8192
#define D 256
#define L 4
#define K 1024
#define E 8

#define TM 128            // samples per dist block
#define TN 128            // codes per dist block
#define BK 32             // k-chunk (one MFMA k-step)
#define KSPLIT (K / TN)   // 8
#define MAXTILES (N / TM + E)   // 72
#define MARGIN 4e-4f

typedef unsigned long long u64;
typedef __attribute__((ext_vector_type(8))) short bf16x8;
typedef __attribute__((ext_vector_type(4))) float f32x4;

__device__ __forceinline__ unsigned f2sort(float f) {
    unsigned u = __float_as_uint(f);
    return (u & 0x80000000u) ? ~u : (u | 0x80000000u);
}
__device__ __forceinline__ float sort2f(unsigned s) {
    unsigned u = (s & 0x80000000u) ? (s & 0x7fffffffu) : ~s;
    return __uint_as_float(u);
}
__device__ __forceinline__ u64 umin64(u64 a, u64 b) { return a < b ? a : b; }
__device__ __forceinline__ u64 umax64(u64 a, u64 b) { return a > b ? a : b; }

// manual RNE f32->bf16 (finite inputs)
__device__ __forceinline__ unsigned short f2bf(float f) {
    unsigned u = __float_as_uint(f);
    unsigned r = (u + 0x7fffu + ((u >> 16) & 1u)) >> 16;
    return (unsigned short)r;
}
__device__ __forceinline__ float bf2f(unsigned short h) {
    return __uint_as_float(((unsigned)h) << 16);
}

__device__ __forceinline__ void gload_lds16(const void* g, void* l) {
    __builtin_amdgcn_global_load_lds(
        (const __attribute__((address_space(1))) unsigned int*)(g),
        (__attribute__((address_space(3))) unsigned int*)(l), 16, 0, 0);
}

// ------------------------------------------------------------- gate ---------
// NOTE: no atomics here — 8192 same-line atomicAdds cost ~98us (R4 counters).
__global__ void gate_kernel(const float* __restrict__ x,
                            const float* __restrict__ gW,
                            const float* __restrict__ gb,
                            int* __restrict__ eid,
                            float* __restrict__ out_idx,
                            unsigned short* __restrict__ rhi,
                            unsigned short* __restrict__ rlo) {
    int wid = threadIdx.x >> 6, lane = threadIdx.x & 63;
    int n = blockIdx.x * 4 + wid;
    float4 xv = *reinterpret_cast<const float4*>(x + (size_t)n * D + lane * 4);

    ushort4 h4, l4;
    h4.x = f2bf(xv.x); l4.x = f2bf(xv.x - bf2f(h4.x));
    h4.y = f2bf(xv.y); l4.y = f2bf(xv.y - bf2f(h4.y));
    h4.z = f2bf(xv.z); l4.z = f2bf(xv.z - bf2f(h4.z));
    h4.w = f2bf(xv.w); l4.w = f2bf(xv.w - bf2f(h4.w));
    *reinterpret_cast<ushort4*>(rhi + (size_t)n * D + lane * 4) = h4;
    *reinterpret_cast<ushort4*>(rlo + (size_t)n * D + lane * 4) = l4;

    float xa[4] = {xv.x, xv.y, xv.z, xv.w};
    float a[8];
#pragma unroll
    for (int e = 0; e < 8; e++) a[e] = 0.f;
    const float* wr = gW + (size_t)(lane * 4) * E;
#pragma unroll
    for (int i = 0; i < 4; i++) {
        float xs = xa[i];
        float4 w0 = *reinterpret_cast<const float4*>(wr + i * E);
        float4 w1 = *reinterpret_cast<const float4*>(wr + i * E + 4);
        a[0] = fmaf(xs, w0.x, a[0]); a[1] = fmaf(xs, w0.y, a[1]);
        a[2] = fmaf(xs, w0.z, a[2]); a[3] = fmaf(xs, w0.w, a[3]);
        a[4] = fmaf(xs, w1.x, a[4]); a[5] = fmaf(xs, w1.y, a[5]);
        a[6] = fmaf(xs, w1.z, a[6]); a[7] = fmaf(xs, w1.w, a[7]);
    }
#pragma unroll
    for (int off = 32; off > 0; off >>= 1) {
#pragma unroll
        for (int e = 0; e < 8; e++) a[e] += __shfl_xor(a[e], off);
    }
    if (lane == 0) {
        int be = 0;
        float bv = a[0] + gb[0];
        for (int e = 1; e < 8; e++) {
            float v = a[e] + gb[e];
            if (v > bv) { bv = v; be = e; }
        }
        eid[n] = be;
        out_idx[(size_t)n * (L + 1) + L] = (float)be;
    }
}

// ---------------- deterministic counting sort by expert (zero atomics) ------
// one block, 256 threads, 32 samples/thread. Per-thread histograms packed as
// 8 x 16-bit fields in two u64 (N=8192 < 2^16, packed adds never carry).
__global__ __launch_bounds__(256)
void bucket_kernel(const int* __restrict__ eid, int* __restrict__ counts,
                   int* __restrict__ order) {
    __shared__ u64 wtot_lo[4], wtot_hi[4];
    __shared__ int base[E];
    int tid = threadIdx.x, lane = tid & 63, wv = tid >> 6;
    int n0 = tid * 32;
    int eids[32];
    u64 lo = 0, hi = 0;
#pragma unroll
    for (int j = 0; j < 32; j++) {
        int e = eid[n0 + j];
        eids[j] = e;
        if (e < 4) lo += 1ull << (e * 16);
        else       hi += 1ull << ((e - 4) * 16);
    }
    // inclusive wave scan (packed)
    u64 slo = lo, shi = hi;
#pragma unroll
    for (int d = 1; d < 64; d <<= 1) {
        u64 t1 = __shfl_up(slo, d);
        u64 t2 = __shfl_up(shi, d);
        if (lane >= d) { slo += t1; shi += t2; }
    }
    if (lane == 63) { wtot_lo[wv] = slo; wtot_hi[wv] = shi; }
    __syncthreads();
    u64 wofflo = 0, woffhi = 0;
    for (int w = 0; w < wv; w++) { wofflo += wtot_lo[w]; woffhi += wtot_hi[w]; }
    u64 exlo = wofflo + slo - lo;   // exclusive prefix for this thread
    u64 exhi = woffhi + shi - hi;
    if (tid == 0) {
        u64 tlo = wtot_lo[0] + wtot_lo[1] + wtot_lo[2] + wtot_lo[3];
        u64 thi = wtot_hi[0] + wtot_hi[1] + wtot_hi[2] + wtot_hi[3];
        int a = 0;
#pragma unroll
        for (int e = 0; e < 4; e++) {
            int c = (int)((tlo >> (e * 16)) & 0xffff);
            counts[e] = c; base[e] = a; a += c;
        }
#pragma unroll
        for (int e = 0; e < 4; e++) {
            int c = (int)((thi >> (e * 16)) & 0xffff);
            counts[4 + e] = c; base[4 + e] = a; a += c;
        }
    }
    __syncthreads();
#pragma unroll
    for (int j = 0; j < 32; j++) {
        int e = eids[j];
        int p;
        if (e < 4) { p = (int)((exlo >> (e * 16)) & 0xffff); exlo += 1ull << (e * 16); }
        else       { p = (int)((exhi >> ((e - 4) * 16)) & 0xffff); exhi += 1ull << ((e - 4) * 16); }
        order[base[e] + p] = n0 + j;
    }
}

// --------------------------------------- codebook prep: c2 + bf16 hi/lo -----
__global__ void cb_prep(const float* __restrict__ cbs, float* __restrict__ c2,
                        unsigned short* __restrict__ cbhi,
                        unsigned short* __restrict__ cblo) {
    int wid = threadIdx.x >> 6, lane = threadIdx.x & 63;
    size_t row = (size_t)blockIdx.x * 4 + wid;
    float4 v = *reinterpret_cast<const float4*>(cbs + row * D + lane * 4);
    ushort4 h4, l4;
    h4.x = f2bf(v.x); l4.x = f2bf(v.x - bf2f(h4.x));
    h4.y = f2bf(v.y); l4.y = f2bf(v.y - bf2f(h4.y));
    h4.z = f2bf(v.z); l4.z = f2bf(v.z - bf2f(h4.z));
    h4.w = f2bf(v.w); l4.w = f2bf(v.w - bf2f(h4.w));
    *reinterpret_cast<ushort4*>(cbhi + row * D + lane * 4) = h4;
    *reinterpret_cast<ushort4*>(cblo + row * D + lane * 4) = l4;
    float s = v.x * v.x + v.y * v.y + v.z * v.z + v.w * v.w;
#pragma unroll
    for (int off = 32; off > 0; off >>= 1) s += __shfl_xor(s, off);
    if (lane == 0) c2[row] = s;
}

// ------------------------------------------------------------ distances -----
// 128x128 tile, bf16x3 MFMA, double-buffered LDS (stage k+1 overlaps MFMA k),
// one barrier per chunk. Writes per-sample (best,second) per 64-code half.
__global__ __launch_bounds__(256, 2)
void dist_kernel(const unsigned short* __restrict__ rhi,
                 const unsigned short* __restrict__ rlo,
                 const unsigned short* __restrict__ cbhi,
                 const unsigned short* __restrict__ cblo,
                 const float* __restrict__ c2l,
                 const int* __restrict__ order, const int* __restrict__ counts,
                 uint4* __restrict__ ws2) {
    __shared__ short lA[2][TM * 64];
    __shared__ short lB[2][TN * 64];

    int bx = blockIdx.x;
    int tile = bx >> 3, kc = bx & 7;

    int eoffL[E + 1]; int a = 0;
#pragma unroll
    for (int i = 0; i < E; i++) { eoffL[i] = a; a += counts[i]; }
    eoffL[E] = a;

    int e = -1, lt = 0, cnt = 0, cum = 0;
    for (int i = 0; i < E; i++) {
        int c = counts[i];
        int t = (c + TM - 1) / TM;
        if (tile < cum + t) { e = i; lt = tile - cum; cnt = c; break; }
        cum += t;
    }
    if (e < 0) return;
    int base = eoffL[e] + lt * TM;
    int mcnt = min(TM, cnt - lt * TM);
    int k0 = kc * TN;

    int tid = threadIdx.x;
    int lane = tid & 63, wv = tid >> 6;
    int wr = wv >> 1, wc = wv & 1;

    int srow[4], scol[4], nid[4];
#pragma unroll
    for (int i = 0; i < 4; i++) {
        int s = i * 256 + tid;
        srow[i] = s >> 3;
        scol[i] = (s & 7) ^ (srow[i] & 7);
        nid[i] = 0;
    }
#pragma unroll
    for (int i = 0; i < 4; i++) nid[i] = order[min(base + srow[i], N - 1)];

    const size_t cbbase = ((size_t)e * K + k0) * D;

    f32x4 acc[4][4];
#pragma unroll
    for (int fr = 0; fr < 4; fr++)
#pragma unroll
        for (int fc = 0; fc < 4; fc++)
            acc[fr][fc] = (f32x4){0.f, 0.f, 0.f, 0.f};

    auto STAGE = [&](int buf, int ck) {
        int dc = ck * BK;
#pragma unroll
        for (int i = 0; i < 4; i++) {
            int s = i * 256 + tid, c = scol[i];
            const unsigned short* src = (c < 4)
                ? (rhi + (size_t)nid[i] * D + dc + c * 8)
                : (rlo + (size_t)nid[i] * D + dc + (c - 4) * 8);
            gload_lds16(src, &lA[buf][s * 8]);
        }
#pragma unroll
        for (int i = 0; i < 4; i++) {
            int s = i * 256 + tid, c = scol[i];
            const unsigned short* src = (c < 4)
                ? (cbhi + cbbase + (size_t)srow[i] * D + dc + c * 8)
                : (cblo + cbbase + (size_t)srow[i] * D + dc + (c - 4) * 8);
            gload_lds16(src, &lB[buf][s * 8]);
        }
    };

    int q = lane >> 4, rL = lane & 15;
    STAGE(0, 0);
    for (int ck = 0; ck < D / BK; ck++) {
        __syncthreads();
        if (ck < D / BK - 1) STAGE((ck + 1) & 1, ck + 1);
        int buf = ck & 1;
        bf16x8 ah[4], al[4];
#pragma unroll
        for (int fr = 0; fr < 4; fr++) {
            int row = wr * 64 + fr * 16 + rL;
            ah[fr] = *reinterpret_cast<const bf16x8*>(&lA[buf][row * 64 + ((q) ^ (row & 7)) * 8]);
            al[fr] = *reinterpret_cast<const bf16x8*>(&lA[buf][row * 64 + ((4 + q) ^ (row & 7)) * 8]);
        }
#pragma unroll
        for (int fc = 0; fc < 4; fc++) {
            int row = wc * 64 + fc * 16 + rL;
            bf16x8 bh = *reinterpret_cast<const bf16x8*>(&lB[buf][row * 64 + ((q) ^ (row & 7)) * 8]);
            bf16x8 bl = *reinterpret_cast<const bf16x8*>(&lB[buf][row * 64 + ((4 + q) ^ (row & 7)) * 8]);
#pragma unroll
            for (int fr = 0; fr < 4; fr++) {
                acc[fr][fc] = __builtin_amdgcn_mfma_f32_16x16x32_bf16(ah[fr], bh, acc[fr][fc], 0, 0, 0);
                acc[fr][fc] = __builtin_amdgcn_mfma_f32_16x16x32_bf16(ah[fr], bl, acc[fr][fc], 0, 0, 0);
                acc[fr][fc] = __builtin_amdgcn_mfma_f32_16x16x32_bf16(al[fr], bh, acc[fr][fc], 0, 0, 0);
            }
        }
    }

    int cL = lane & 15;
#pragma unroll
    for (int fr = 0; fr < 4; fr++) {
#pragma unroll
        for (int j = 0; j < 4; j++) {
            int row_local = wr * 64 + fr * 16 + q * 4 + j;
            u64 best = ~0ull; unsigned sec = 0xFFFFFFFFu;
#pragma unroll
            for (int fc = 0; fc < 4; fc++) {
                int col = k0 + wc * 64 + fc * 16 + cL;
                float dist = c2l[e * K + col] - 2.0f * acc[fr][fc][j];
                u64 kk = ((u64)f2sort(dist) << 32) | (unsigned)col;
                u64 mx = umax64(best, kk);
                best = umin64(best, kk);
                sec = min(sec, (unsigned)(mx >> 32));
            }
#pragma unroll
            for (int m = 1; m < 16; m <<= 1) {
                u64 ob = __shfl_xor(best, m, 16);
                unsigned os = __shfl_xor(sec, m, 16);
                u64 mx = umax64(best, ob);
                best = umin64(best, ob);
                sec = min(min(sec, os), (unsigned)(mx >> 32));
            }
            if (cL == 0 && row_local < mcnt) {
                int n = order[base + row_local];
                uint4 v;
                v.x = (unsigned)(best & 0xffffffffu);
                v.y = (unsigned)(best >> 32);
                v.z = sec; v.w = 0;
                ws2[(size_t)n * 16 + kc * 2 + wc] = v;
            }
        }
    }
}

// ---------------- resolve + block-cooperative exact rescore + update --------
__global__ __launch_bounds__(256)
void finalize_kernel(const float* __restrict__ rin, float* __restrict__ resid,
                     const float* __restrict__ cbl, const uint4* __restrict__ ws2,
                     const int* __restrict__ eid, const float* __restrict__ x,
                     float* __restrict__ out, float* __restrict__ lossb,
                     const float* __restrict__ c2l,
                     unsigned short* __restrict__ rhi,
                     unsigned short* __restrict__ rlo, int l) {
    __shared__ int s_idx[32];
    __shared__ int s_eid[32];
    __shared__ int s_flag[32];
    __shared__ int s_fcount;
    __shared__ u64 s_rb[4];
    __shared__ float s_ls[4];

    int tid = threadIdx.x, lane = tid & 63, wv = tid >> 6;
    int n0 = blockIdx.x * 32;
    if (tid == 0) s_fcount = 0;
    __syncthreads();

#pragma unroll
    for (int pass = 0; pass < 2; pass++) {
        int sloc = wv * 8 + pass * 4 + (lane >> 4);
        int n = n0 + sloc;
        int l16 = lane & 15;
        uint4 ev = ws2[(size_t)n * 16 + l16];
        u64 best = ((u64)ev.y << 32) | ev.x;
        unsigned sec = ev.z;
#pragma unroll
        for (int m = 1; m < 16; m <<= 1) {
            u64 ob = __shfl_xor(best, m, 16);
            unsigned os = __shfl_xor(sec, m, 16);
            u64 mx = umax64(best, ob);
            best = umin64(best, ob);
            sec = min(min(sec, os), (unsigned)(mx >> 32));
        }
        if (l16 == 0) {
            s_idx[sloc] = (int)(best & 0xffffffffu);
            s_eid[sloc] = eid[n];
            float bd = sort2f((unsigned)(best >> 32));
            float sd = sort2f(sec);
            if (sd - bd < MARGIN) {
                int p = atomicAdd(&s_fcount, 1);
                s_flag[p] = sloc;
            }
        }
    }
    __syncthreads();
    int fc = s_fcount;

    for (int f = 0; f < fc; f++) {
        int sloc = s_flag[f];
        int n = n0 + sloc, e = s_eid[sloc];
        const float* rrow = rin + (size_t)n * D;
        u64 rb = ~0ull;
        for (int c = 0; c < 4; c++) {
            int k = c * 256 + tid;
            const float* crow = cbl + ((size_t)e * K + k) * D;
            float dot = 0.f;
#pragma unroll
            for (int d0 = 0; d0 < D; d0 += 4) {
                float4 c4 = *reinterpret_cast<const float4*>(crow + d0);
                float4 s4 = *reinterpret_cast<const float4*>(rrow + d0);
                dot = fmaf(s4.x, c4.x, dot);
                dot = fmaf(s4.y, c4.y, dot);
                dot = fmaf(s4.z, c4.z, dot);
                dot = fmaf(s4.w, c4.w, dot);
            }
            float dist = c2l[e * K + k] - 2.0f * dot;
            rb = umin64(rb, ((u64)f2sort(dist) << 32) | (unsigned)k);
        }
#pragma unroll
        for (int m = 1; m < 64; m <<= 1) rb = umin64(rb, __shfl_xor(rb, m));
        if (lane == 0) s_rb[wv] = rb;
        __syncthreads();
        if (tid == 0) {
            rb = umin64(umin64(s_rb[0], s_rb[1]), umin64(s_rb[2], s_rb[3]));
            s_idx[sloc] = (int)(rb & 0xffffffffu);
        }
        __syncthreads();
    }

    float lsum = 0.f;
#pragma unroll
    for (int i = 0; i < 8; i++) {
        int c = i * 256 + tid;
        int sloc = c >> 6, f4p = c & 63;
        int n = n0 + sloc;
        int e = s_eid[sloc], idx = s_idx[sloc];
        const float* qrow = cbl + ((size_t)e * K + idx) * D;
        float4 q4 = *reinterpret_cast<const float4*>(qrow + f4p * 4);
        float4 r4 = *reinterpret_cast<const float4*>(rin + (size_t)n * D + f4p * 4);
        float dx = q4.x - r4.x, dy = q4.y - r4.y, dz = q4.z - r4.z, dw = q4.w - r4.w;
        lsum += dx * dx + dy * dy + dz * dz + dw * dw;
        float4 nr = make_float4(r4.x - q4.x, r4.y - q4.y, r4.z - q4.z, r4.w - q4.w);
        if (l < L - 1) {
            *reinterpret_cast<float4*>(resid + (size_t)n * D + f4p * 4) = nr;
            ushort4 h4, l4w;
            h4.x = f2bf(nr.x); l4w.x = f2bf(nr.x - bf2f(h4.x));
            h4.y = f2bf(nr.y); l4w.y = f2bf(nr.y - bf2f(h4.y));
            h4.z = f2bf(nr.z); l4w.z = f2bf(nr.z - bf2f(h4.z));
            h4.w = f2bf(nr.w); l4w.w = f2bf(nr.w - bf2f(h4.w));
            *reinterpret_cast<ushort4*>(rhi + (size_t)n * D + f4p * 4) = h4;
            *reinterpret_cast<ushort4*>(rlo + (size_t)n * D + f4p * 4) = l4w;
        } else {
            float4 x4 = *reinterpret_cast<const float4*>(x + (size_t)n * D + f4p * 4);
            float4 xq = make_float4(x4.x - nr.x, x4.y - nr.y, x4.z - nr.z, x4.w - nr.w);
            *reinterpret_cast<float4*>(out + (size_t)n * D + f4p * 4) = xq;
        }
        if (f4p == 0)
            out[(size_t)N * D + 1 + (size_t)n * (L + 1) + l] = (float)idx;
    }
#pragma unroll
    for (int m = 1; m < 64; m <<= 1) lsum += __shfl_xor(lsum, m);
    if (lane == 0) s_ls[wv] = lsum;
    __syncthreads();
    if (tid == 0)
        atomicAdd(&lossb[blockIdx.x & 31], s_ls[0] + s_ls[1] + s_ls[2] + s_ls[3]);
}

__global__ void loss_fin_kernel(const float* __restrict__ lossb, float* __restrict__ out) {
    float s = 0.f;
    for (int i = 0; i < 32; i++) s += lossb[i];
    out[(size_t)N * D] = 2.0f * s / ((float)N * (float)D * (float)L);
}

// ----------------------------------------------------------------------------
extern "C" void kernel_launch(void* const* d_in, const int* in_sizes, int n_in,
                              void* d_out, int out_size, void* d_ws, size_t ws_size,
                              hipStream_t stream) {
    const float* x   = (const float*)d_in[0];
    // d_in[1] = labels (unused)
    const float* cbs = (const float*)d_in[2];
    const float* gW  = (const float*)d_in[3];
    const float* gb  = (const float*)d_in[4];
    float* out = (float*)d_out;

    char* ws = (char*)d_ws;
    float*          resid = (float*)(ws);                       //  8,388,608
    unsigned short* rhi   = (unsigned short*)(ws + 8388608);    //  4,194,304
    unsigned short* rlo   = (unsigned short*)(ws + 12582912);   //  4,194,304
    unsigned short* cbhi  = (unsigned short*)(ws + 16777216);   // 16,777,216
    unsigned short* cblo  = (unsigned short*)(ws + 33554432);   // 16,777,216
    float*          c2    = (float*)(ws + 50331648);            //    131,072
    int*            eid   = (int*)(ws + 50462720);              //     32,768
    int*            order = (int*)(ws + 50495488);              //     33,280
    uint4*          ws2   = (uint4*)(ws + 50528768);            //  2,097,152
    char*           smallp = ws + 52625920;
    int*   counts  = (int*)(smallp);          // 32 B
    float* lossb   = (float*)(smallp + 128);  // 128 B (32 buckets)

    hipMemsetAsync(smallp, 0, 256, stream);

    gate_kernel<<<N / 4, 256, 0, stream>>>(x, gW, gb, eid,
                                           out + (size_t)N * D + 1, rhi, rlo);
    bucket_kernel<<<1, 256, 0, stream>>>(eid, counts, order);
    cb_prep<<<(L * E * K) / 4, 256, 0, stream>>>(cbs, c2, cbhi, cblo);

    for (int l = 0; l < L; l++) {
        const float* rin = (l == 0) ? x : resid;
        size_t cboff = (size_t)l * E * K * D;
        const float* c2l = c2 + (size_t)l * E * K;
        dist_kernel<<<MAXTILES * KSPLIT, 256, 0, stream>>>(
            rhi, rlo, cbhi + cboff, cblo + cboff, c2l, order, counts, ws2);
        finalize_kernel<<<N / 32, 256, 0, stream>>>(
            rin, resid, cbs + cboff, ws2, eid, x, out, lossb, c2l, rhi, rlo, l);
    }
    loss_fin_kernel<<<1, 1, 0, stream>>>(lossb, out);
}